// Round 6
// baseline (767.668 us; speedup 1.0000x reference)
//
#include <hip/hip_runtime.h>
#include <hip/hip_bf16.h>
#include <cstdint>
#include <cstddef>

static inline size_t align_up(size_t x, size_t a) { return (x + a - 1) & ~(a - 1); }

typedef __attribute__((ext_vector_type(4))) float f32x4;
typedef __attribute__((ext_vector_type(8))) short bf16x8;

__device__ inline float bf2f(unsigned int u16) {        // low 16 bits hold bf16
    return __uint_as_float(u16 << 16);
}
__device__ inline unsigned short f2bf(float f) {        // round-to-nearest-even
    unsigned int u = __float_as_uint(f);
    u = (u + 0x7fffu + ((u >> 16) & 1u)) >> 16;
    return (unsigned short)u;
}

#define GLD_LDS(gp, lp) \
    __builtin_amdgcn_global_load_lds( \
        (const __attribute__((address_space(1))) unsigned int*)(gp), \
        (__attribute__((address_space(3))) unsigned int*)(lp), 16, 0, 0)

// ---------------------------------------------------------------------------
__global__ void zero_kernel(int* __restrict__ p, int n) {
    int i = blockIdx.x * 256 + threadIdx.x;
    if (i < n) p[i] = 0;
}

// Edge-encoding detection, single block, sampled, no atomics.
__global__ void detect_kernel(const int* __restrict__ e, int* __restrict__ nz, int E) {
    int t = threadIdx.x;  // 0..255, one block
    long long stride = (long long)E / 4096;
    if (stride < 1) stride = 1;
    int any = 0;
    for (int k = 0; k < 16; ++k) {
        long long idx = (long long)(t * 16 + k) * stride;
        if (idx < E && e[2 * idx + 1] != 0) any = 1;
    }
    if (any) nz[0] = 1;  // same-value race is benign
}

__global__ void conv_count_kernel(const int* __restrict__ eraw, const int* __restrict__ nz,
                                  int* __restrict__ src32, int* __restrict__ dst32,
                                  int* __restrict__ cnt, int E) {
    int i = blockIdx.x * blockDim.x + threadIdx.x;
    if (i >= E) return;
    int s, d;
    if (*nz == 0) {  // int64 storage
        const long long* e64 = (const long long*)eraw;
        s = (int)e64[i];
        d = (int)e64[i + E];
    } else {         // int32 storage
        s = eraw[i];
        d = eraw[i + E];
    }
    src32[i] = s;
    dst32[i] = d;
    atomicAdd(&cnt[d], 1);
}

// 3-kernel exclusive scan over cnt[0..n) -> offs[0..n]
__global__ void scan1_kernel(const int* __restrict__ cnt, int* __restrict__ partial,
                             int n, int C) {
    int t = blockIdx.x * 256 + threadIdx.x;  // 0..1023
    int s = 0;
    int base = t * C;
    for (int i = 0; i < C; ++i) {
        int idx = base + i;
        if (idx < n) s += cnt[idx];
    }
    partial[t] = s;
}

__global__ void __launch_bounds__(1024) scan2_kernel(int* __restrict__ partial) {
    __shared__ int sh[1024];
    int t = threadIdx.x;
    sh[t] = partial[t];
    __syncthreads();
    for (int off = 1; off < 1024; off <<= 1) {
        int v = (t >= off) ? sh[t - off] : 0;
        __syncthreads();
        sh[t] += v;
        __syncthreads();
    }
    partial[t] = (t == 0) ? 0 : sh[t - 1];  // exclusive
}

__global__ void scan3_kernel(const int* __restrict__ cnt, const int* __restrict__ partial,
                             int* __restrict__ offs, int n, int C, int E) {
    int t = blockIdx.x * 256 + threadIdx.x;
    int run = partial[t];
    int base = t * C;
    for (int i = 0; i < C; ++i) {
        int idx = base + i;
        if (idx < n) {
            offs[idx] = run;
            run += cnt[idx];
        }
    }
    if (t == 0) offs[n] = E;
}

__global__ void inv_kernel(const int* __restrict__ cnt, float* __restrict__ inv, int n) {
    int i = blockIdx.x * 256 + threadIdx.x;
    if (i < n) inv[i] = 1.0f / (float)max(cnt[i], 1);
}

__global__ void fill_kernel(const int* __restrict__ src32, const int* __restrict__ dst32,
                            const int* __restrict__ offs, int* __restrict__ cursor,
                            int* __restrict__ sorted, int E) {
    int i = blockIdx.x * 256 + threadIdx.x;
    if (i >= E) return;
    int d = dst32[i];
    int p = offs[d] + atomicAdd(&cursor[d], 1);
    sorted[p] = src32[i];
}

// fp32 -> bf16, vectorized x4
__global__ void cvt_bf16_kernel(const float* __restrict__ x, unsigned short* __restrict__ xb,
                                int n4) {
    int i = blockIdx.x * 256 + threadIdx.x;
    if (i >= n4) return;
    float4 v = *(const float4*)(x + (size_t)i * 4);
    uint2 o;
    o.x = (unsigned int)f2bf(v.x) | ((unsigned int)f2bf(v.y) << 16);
    o.y = (unsigned int)f2bf(v.z) | ((unsigned int)f2bf(v.w) << 16);
    *(uint2*)(xb + (size_t)i * 4) = o;
}

// ---------------------------------------------------------------------------
// Chunked mean aggregation (512-dim): feature dim split into 16 chunks of 32.
// X is CHUNK-MAJOR: Xc[chunk][Mpad][32] bf16 -> 3.2 MB per chunk fits each
// XCD's 4 MB L2 (round-5: row-major random gather left 375 MB of L2 misses).
// grid.y = chunk (slow axis -> co-resident blocks share a chunk).
// Lane mapping: 16 nodes/wave x 4 lanes/node (16B each of the 64B chunk row).
// ---------------------------------------------------------------------------
__global__ void __launch_bounds__(256) agg512c_kernel(
    const unsigned short* __restrict__ Xc, const int* __restrict__ srt,
    const int* __restrict__ offs, const float* __restrict__ invc,
    unsigned short* __restrict__ outc, int nNodes, int Mpad) {
    const int chunk = blockIdx.y;
    const int wave = threadIdx.x >> 6;
    const int lane = threadIdx.x & 63;
    const int g = lane >> 2;   // node sub-index 0..15
    const int d = lane & 3;    // 16B quarter of the 64B chunk row
    const int node = (blockIdx.x * 4 + wave) * 16 + g;
    if (node >= nNodes) return;
    const int beg = offs[node], end = offs[node + 1];
    const float sc = invc[node];
    const unsigned short* base = Xc + (size_t)chunk * Mpad * 32 + d * 8;
    float a0 = 0.f, a1 = 0.f, a2 = 0.f, a3 = 0.f, a4 = 0.f, a5 = 0.f, a6 = 0.f, a7 = 0.f;
#define ACC8(v)                                \
    do {                                       \
        a0 += bf2f((v).x & 0xffffu);           \
        a1 += bf2f((v).x >> 16);               \
        a2 += bf2f((v).y & 0xffffu);           \
        a3 += bf2f((v).y >> 16);               \
        a4 += bf2f((v).z & 0xffffu);           \
        a5 += bf2f((v).z >> 16);               \
        a6 += bf2f((v).w & 0xffffu);           \
        a7 += bf2f((v).w >> 16);               \
    } while (0)
    int e = beg;
    for (; e + 4 <= end; e += 4) {
        int s0 = srt[e], s1 = srt[e + 1], s2 = srt[e + 2], s3 = srt[e + 3];
        uint4 v0 = *(const uint4*)(base + (size_t)s0 * 32);
        uint4 v1 = *(const uint4*)(base + (size_t)s1 * 32);
        uint4 v2 = *(const uint4*)(base + (size_t)s2 * 32);
        uint4 v3 = *(const uint4*)(base + (size_t)s3 * 32);
        ACC8(v0); ACC8(v1); ACC8(v2); ACC8(v3);
    }
    for (; e < end; ++e) {
        uint4 v = *(const uint4*)(base + (size_t)srt[e] * 32);
        ACC8(v);
    }
#undef ACC8
    uint4 o;
    o.x = (unsigned int)f2bf(a0 * sc) | ((unsigned int)f2bf(a1 * sc) << 16);
    o.y = (unsigned int)f2bf(a2 * sc) | ((unsigned int)f2bf(a3 * sc) << 16);
    o.z = (unsigned int)f2bf(a4 * sc) | ((unsigned int)f2bf(a5 * sc) << 16);
    o.w = (unsigned int)f2bf(a6 * sc) | ((unsigned int)f2bf(a7 * sc) << 16);
    *(uint4*)(outc + ((size_t)chunk * Mpad + node) * 32 + d * 8) = o;
}

// Layer-0 aggregation: 128-dim from row-major xb, writes CHUNK-MAJOR (4 chunks).
__global__ void __launch_bounds__(256) agg128_kernel(
    const unsigned short* __restrict__ X, const int* __restrict__ srt,
    const int* __restrict__ offs, const float* __restrict__ invc,
    unsigned short* __restrict__ outc, int nNodes, int Mpad) {
    int node = blockIdx.x * 4 + (threadIdx.x >> 6);
    if (node >= nNodes) return;
    int lane = threadIdx.x & 63;
    const unsigned short* xp = X + (size_t)lane * 2;
    int beg = offs[node], end = offs[node + 1];
    float sc = invc[node];
    float a0 = 0.f, a1 = 0.f;
    int e = beg;
    for (; e + 4 <= end; e += 4) {
        int s0 = srt[e], s1 = srt[e + 1], s2 = srt[e + 2], s3 = srt[e + 3];
        unsigned int v0 = *(const unsigned int*)(xp + (size_t)s0 * 128);
        unsigned int v1 = *(const unsigned int*)(xp + (size_t)s1 * 128);
        unsigned int v2 = *(const unsigned int*)(xp + (size_t)s2 * 128);
        unsigned int v3 = *(const unsigned int*)(xp + (size_t)s3 * 128);
        a0 += bf2f(v0 & 0xffffu) + bf2f(v1 & 0xffffu) + bf2f(v2 & 0xffffu) + bf2f(v3 & 0xffffu);
        a1 += bf2f(v0 >> 16) + bf2f(v1 >> 16) + bf2f(v2 >> 16) + bf2f(v3 >> 16);
    }
    for (; e < end; ++e) {
        unsigned int v = *(const unsigned int*)(xp + (size_t)srt[e] * 128);
        a0 += bf2f(v & 0xffffu);
        a1 += bf2f(v >> 16);
    }
    unsigned int o = (unsigned int)f2bf(a0 * sc) | ((unsigned int)f2bf(a1 * sc) << 16);
    int f = lane * 2;  // feature index
    *(unsigned int*)(outc + ((size_t)(f >> 5) * Mpad + node) * 32 + (f & 31)) = o;
}

// ---------------------------------------------------------------------------
// MFMA SAGE GEMM, wide-N tile: C = relu?( Aagg @ Wl^T + Aself @ Wr^T + bias )
// A operands use generalized strides: elem addr = kblk*KBS + row*RS + kE,
// supporting row-major (KBS=32, RS=K) and chunk-major (KBS=Mpad*32, RS=32).
// bf16 output is written CHUNK-MAJOR [n/32][Mpad][32] for the next layer's
// L2-resident aggregation; fp32 output (final) is row-major.
// Tile 128(M) x 256(N), BK=32. 4 waves, each owns 64x128 (4x8 16x16x32 frags).
// ---------------------------------------------------------------------------
__global__ void __launch_bounds__(256, 2) sage_gemm_mfma(
    const unsigned short* __restrict__ Aagg, long long kbsa, int rsa,
    const unsigned short* __restrict__ Aself, long long kbss, int rss,
    const unsigned short* __restrict__ Wlb, const unsigned short* __restrict__ Wrb,
    const float* __restrict__ bias, void* __restrict__ Cout,
    int M, int N, int K, int relu, int out_bf16, int outMpad) {
    __shared__ __attribute__((aligned(16))) unsigned short As[128 * 32];  //  8 KB
    __shared__ __attribute__((aligned(16))) unsigned short Bs[256 * 32];  // 16 KB
    const int tid = threadIdx.x;
    const int lane = tid & 63;
    const int wave = tid >> 6;
    const int wm = wave >> 1, wn = wave & 1;          // 2x2 wave grid
    const int m0 = blockIdx.y * 128, n0 = blockIdx.x * 256;

    f32x4 acc[4][8];
#pragma unroll
    for (int i = 0; i < 4; ++i)
#pragma unroll
        for (int j = 0; j < 8; ++j) acc[i][j] = (f32x4){0.f, 0.f, 0.f, 0.f};

    const int srow = wave * 16 + (lane >> 2);  // staged row within 64-row chunk
    const int kE = (lane & 3) * 8;             // 16B piece within 64B k-slice

    const int frow = lane & 15;        // m (A) / n (B) within 16-tile
    const int kk = (lane >> 4) * 8;    // k start within BK=32

    for (int pass = 0; pass < 2; ++pass) {
        const unsigned short* A = pass ? Aself : Aagg;
        const long long kbs = pass ? kbss : kbsa;
        const int rs = pass ? rss : rsa;
        const unsigned short* W = pass ? Wrb : Wlb;
        for (int k0 = 0; k0 < K; k0 += 32) {
            const long long kb = (long long)(k0 >> 5) * kbs;
            __syncthreads();  // LDS readers of previous tile done
            // A-tile: 128 rows, chunks c=0,1 -> rows c*64 + srow
            GLD_LDS(A + kb + (size_t)(m0 + 0 * 64 + srow) * rs + kE, &As[0 * 2048 + wave * 512]);
            GLD_LDS(A + kb + (size_t)(m0 + 1 * 64 + srow) * rs + kE, &As[1 * 2048 + wave * 512]);
            // W-tile: 256 rows (row-major [N,K]), chunks c=0..3
            GLD_LDS(W + (size_t)(n0 + 0 * 64 + srow) * K + k0 + kE, &Bs[0 * 2048 + wave * 512]);
            GLD_LDS(W + (size_t)(n0 + 1 * 64 + srow) * K + k0 + kE, &Bs[1 * 2048 + wave * 512]);
            GLD_LDS(W + (size_t)(n0 + 2 * 64 + srow) * K + k0 + kE, &Bs[2 * 2048 + wave * 512]);
            GLD_LDS(W + (size_t)(n0 + 3 * 64 + srow) * K + k0 + kE, &Bs[3 * 2048 + wave * 512]);
            __syncthreads();  // staging complete (barrier drains vmcnt)
            bf16x8 af[4], bfr[8];
#pragma unroll
            for (int t = 0; t < 4; ++t)
                af[t] = *(const bf16x8*)&As[(wm * 64 + t * 16 + frow) * 32 + kk];
#pragma unroll
            for (int t = 0; t < 8; ++t)
                bfr[t] = *(const bf16x8*)&Bs[(wn * 128 + t * 16 + frow) * 32 + kk];
#pragma unroll
            for (int i = 0; i < 4; ++i)
#pragma unroll
                for (int j = 0; j < 8; ++j)
                    acc[i][j] = __builtin_amdgcn_mfma_f32_16x16x32_bf16(
                        af[i], bfr[j], acc[i][j], 0, 0, 0);
        }
    }

    // epilogue: C/D layout col=lane&15, row=(lane>>4)*4+reg
    const int col = lane & 15;
    const int rgrp = (lane >> 4) * 4;
#pragma unroll
    for (int j = 0; j < 8; ++j) {
        int n = n0 + wn * 128 + j * 16 + col;
        float bv = bias[n];
        size_t cbase = ((size_t)(n >> 5) * outMpad) * 32 + (n & 31);
#pragma unroll
        for (int i = 0; i < 4; ++i) {
            int mBase = m0 + wm * 64 + i * 16 + rgrp;
#pragma unroll
            for (int r = 0; r < 4; ++r) {
                int m = mBase + r;
                if (m >= M) continue;
                float v = acc[i][j][r] + bv;
                if (relu) v = fmaxf(v, 0.f);
                if (out_bf16)
                    ((unsigned short*)Cout)[cbase + (size_t)m * 32] = f2bf(v);
                else
                    ((float*)Cout)[(size_t)m * N + n] = v;
            }
        }
    }
}

// ---------------------------------------------------------------------------
extern "C" void kernel_launch(void* const* d_in, const int* in_sizes, int n_in,
                              void* d_out, int out_size, void* d_ws, size_t ws_size,
                              hipStream_t stream) {
    const float* x   = (const float*)d_in[0];
    const int*   e   = (const int*)d_in[1];
    const float* Wl0 = (const float*)d_in[2];
    const float* bl0 = (const float*)d_in[3];
    const float* Wr0 = (const float*)d_in[4];
    const float* Wl1 = (const float*)d_in[5];
    const float* bl1 = (const float*)d_in[6];
    const float* Wr1 = (const float*)d_in[7];
    const float* Wl2 = (const float*)d_in[8];
    const float* bl2 = (const float*)d_in[9];
    const float* Wr2 = (const float*)d_in[10];
    float* out = (float*)d_out;

    const int N = in_sizes[0] / 128;           // 50000 nodes
    const int E = in_sizes[1] / 2;             // 800000 edges
    const int Mpad = ((N + 127) / 128) * 128;  // 50048: GEMM staging never OOB

    char* ws = (char*)d_ws;
    size_t off = 0;
    auto alloc = [&](size_t bytes) { size_t o = off; off = align_up(off + bytes, 512); return o; };

    size_t o_nz     = alloc(4);
    size_t o_cnt    = alloc((size_t)N * 4);
    size_t o_cursor = alloc((size_t)N * 4);
    size_t zero_end = off;                       // [0, zero_end) zeroed each call
    size_t o_part   = alloc(1024 * 4);
    size_t o_offs   = alloc((size_t)(N + 1) * 4);
    size_t o_inv    = alloc((size_t)N * 4);
    size_t o_src    = alloc((size_t)E * 4);
    size_t o_dst    = alloc((size_t)E * 4);
    size_t o_sort   = alloc((size_t)E * 4);
    size_t o_xb     = alloc((size_t)Mpad * 128 * 2);   // bf16 x, row-major
    size_t o_aggc   = alloc((size_t)Mpad * 512 * 2);   // bf16 agg, chunk-major [16][Mpad][32]
    size_t o_h0c    = alloc((size_t)Mpad * 512 * 2);   // bf16 h0, chunk-major
    size_t o_h1c    = alloc((size_t)Mpad * 512 * 2);   // bf16 h1, chunk-major
    size_t o_wl0    = alloc((size_t)512 * 128 * 2);
    size_t o_wr0    = alloc((size_t)512 * 128 * 2);
    size_t o_wl1    = alloc((size_t)512 * 512 * 2);
    size_t o_wr1    = alloc((size_t)512 * 512 * 2);
    size_t o_wl2    = alloc((size_t)256 * 512 * 2);
    size_t o_wr2    = alloc((size_t)256 * 512 * 2);
    (void)ws_size; (void)n_in; (void)out_size;

    int*            nz     = (int*)(ws + o_nz);
    int*            cnt    = (int*)(ws + o_cnt);
    int*            cursor = (int*)(ws + o_cursor);
    int*            part   = (int*)(ws + o_part);
    int*            offs   = (int*)(ws + o_offs);
    float*          inv    = (float*)(ws + o_inv);
    int*            src32  = (int*)(ws + o_src);
    int*            dst32  = (int*)(ws + o_dst);
    int*            sorted = (int*)(ws + o_sort);
    unsigned short* xb     = (unsigned short*)(ws + o_xb);
    unsigned short* aggc   = (unsigned short*)(ws + o_aggc);
    unsigned short* h0c    = (unsigned short*)(ws + o_h0c);
    unsigned short* h1c    = (unsigned short*)(ws + o_h1c);
    unsigned short* wl0b   = (unsigned short*)(ws + o_wl0);
    unsigned short* wr0b   = (unsigned short*)(ws + o_wr0);
    unsigned short* wl1b   = (unsigned short*)(ws + o_wl1);
    unsigned short* wr1b   = (unsigned short*)(ws + o_wr1);
    unsigned short* wl2b   = (unsigned short*)(ws + o_wl2);
    unsigned short* wr2b   = (unsigned short*)(ws + o_wr2);

    // zero nz/cnt/cursor (ws poisoned 0xAA before every call)
    int zn = (int)(zero_end / 4);
    zero_kernel<<<(zn + 255) / 256, 256, 0, stream>>>((int*)ws, zn);

    int eb = (E + 255) / 256;
    detect_kernel<<<1, 256, 0, stream>>>(e, nz, E);
    conv_count_kernel<<<eb, 256, 0, stream>>>(e, nz, src32, dst32, cnt, E);

    const int C = (N + 1023) / 1024;
    scan1_kernel<<<4, 256, 0, stream>>>(cnt, part, N, C);
    scan2_kernel<<<1, 1024, 0, stream>>>(part);
    scan3_kernel<<<4, 256, 0, stream>>>(cnt, part, offs, N, C, E);
    inv_kernel<<<(N + 255) / 256, 256, 0, stream>>>(cnt, inv, N);
    fill_kernel<<<eb, 256, 0, stream>>>(src32, dst32, offs, cursor, sorted, E);

    // conversions to bf16
    int n4 = N * 128 / 4;
    cvt_bf16_kernel<<<(n4 + 255) / 256, 256, 0, stream>>>(x, xb, n4);
    cvt_bf16_kernel<<<(512 * 128 / 4 + 255) / 256, 256, 0, stream>>>(Wl0, wl0b, 512 * 128 / 4);
    cvt_bf16_kernel<<<(512 * 128 / 4 + 255) / 256, 256, 0, stream>>>(Wr0, wr0b, 512 * 128 / 4);
    cvt_bf16_kernel<<<(512 * 512 / 4 + 255) / 256, 256, 0, stream>>>(Wl1, wl1b, 512 * 512 / 4);
    cvt_bf16_kernel<<<(512 * 512 / 4 + 255) / 256, 256, 0, stream>>>(Wr1, wr1b, 512 * 512 / 4);
    cvt_bf16_kernel<<<(256 * 512 / 4 + 255) / 256, 256, 0, stream>>>(Wl2, wl2b, 256 * 512 / 4);
    cvt_bf16_kernel<<<(256 * 512 / 4 + 255) / 256, 256, 0, stream>>>(Wr2, wr2b, 256 * 512 / 4);

    const int aggBlocks = (N + 3) / 4;
    const int cBlocks = (N + 63) / 64;        // 16 nodes/wave x 4 waves
    const int mBlocks = Mpad / 128;
    const long long KBSC = (long long)Mpad * 32;  // chunk-major k-block stride
    const int RSC = 32;                            // chunk-major row stride

    // Layer 0: 128 -> 512, relu, bf16 chunk-major out
    agg128_kernel<<<aggBlocks, 256, 0, stream>>>(xb, sorted, offs, inv, aggc, N, Mpad);
    sage_gemm_mfma<<<dim3(2, mBlocks), 256, 0, stream>>>(
        aggc, KBSC, RSC, xb, 32, 128, wl0b, wr0b, bl0, h0c, N, 512, 128, 1, 1, Mpad);

    // Layer 1: 512 -> 512, relu, bf16 chunk-major out
    agg512c_kernel<<<dim3(cBlocks, 16), 256, 0, stream>>>(h0c, sorted, offs, inv, aggc, N, Mpad);
    sage_gemm_mfma<<<dim3(2, mBlocks), 256, 0, stream>>>(
        aggc, KBSC, RSC, h0c, KBSC, RSC, wl1b, wr1b, bl1, h1c, N, 512, 512, 1, 1, Mpad);

    // Layer 2: 512 -> 256, no relu, fp32 row-major out
    agg512c_kernel<<<dim3(cBlocks, 16), 256, 0, stream>>>(h1c, sorted, offs, inv, aggc, N, Mpad);
    sage_gemm_mfma<<<dim3(1, mBlocks), 256, 0, stream>>>(
        aggc, KBSC, RSC, h1c, KBSC, RSC, wl2b, wr2b, bl2, out, N, 256, 512, 0, 0, Mpad);
}

// Round 7
// 746.779 us; speedup vs baseline: 1.0280x; 1.0280x over previous
//
#include <hip/hip_runtime.h>
#include <hip/hip_bf16.h>
#include <cstdint>
#include <cstddef>

static inline size_t align_up(size_t x, size_t a) { return (x + a - 1) & ~(a - 1); }

typedef __attribute__((ext_vector_type(4))) float f32x4;
typedef __attribute__((ext_vector_type(8))) short bf16x8;

__device__ inline float bf2f(unsigned int u16) {        // low 16 bits hold bf16
    return __uint_as_float(u16 << 16);
}
__device__ inline unsigned short f2bf(float f) {        // round-to-nearest-even
    unsigned int u = __float_as_uint(f);
    u = (u + 0x7fffu + ((u >> 16) & 1u)) >> 16;
    return (unsigned short)u;
}

#define GLD_LDS(gp, lp) \
    __builtin_amdgcn_global_load_lds( \
        (const __attribute__((address_space(1))) unsigned int*)(gp), \
        (__attribute__((address_space(3))) unsigned int*)(lp), 16, 0, 0)

// ---------------------------------------------------------------------------
__global__ void zero_kernel(int* __restrict__ p, int n) {
    int i = blockIdx.x * 256 + threadIdx.x;
    if (i < n) p[i] = 0;
}

// Edge-encoding detection, single block, sampled, no atomics.
__global__ void detect_kernel(const int* __restrict__ e, int* __restrict__ nz, int E) {
    int t = threadIdx.x;  // 0..255, one block
    long long stride = (long long)E / 4096;
    if (stride < 1) stride = 1;
    int any = 0;
    for (int k = 0; k < 16; ++k) {
        long long idx = (long long)(t * 16 + k) * stride;
        if (idx < E && e[2 * idx + 1] != 0) any = 1;
    }
    if (any) nz[0] = 1;  // same-value race is benign
}

__global__ void conv_count_kernel(const int* __restrict__ eraw, const int* __restrict__ nz,
                                  int* __restrict__ src32, int* __restrict__ dst32,
                                  int* __restrict__ cnt, int E) {
    int i = blockIdx.x * blockDim.x + threadIdx.x;
    if (i >= E) return;
    int s, d;
    if (*nz == 0) {  // int64 storage
        const long long* e64 = (const long long*)eraw;
        s = (int)e64[i];
        d = (int)e64[i + E];
    } else {         // int32 storage
        s = eraw[i];
        d = eraw[i + E];
    }
    src32[i] = s;
    dst32[i] = d;
    atomicAdd(&cnt[d], 1);
}

// 3-kernel exclusive scan over cnt[0..n) -> offs[0..n]
__global__ void scan1_kernel(const int* __restrict__ cnt, int* __restrict__ partial,
                             int n, int C) {
    int t = blockIdx.x * 256 + threadIdx.x;  // 0..1023
    int s = 0;
    int base = t * C;
    for (int i = 0; i < C; ++i) {
        int idx = base + i;
        if (idx < n) s += cnt[idx];
    }
    partial[t] = s;
}

__global__ void __launch_bounds__(1024) scan2_kernel(int* __restrict__ partial) {
    __shared__ int sh[1024];
    int t = threadIdx.x;
    sh[t] = partial[t];
    __syncthreads();
    for (int off = 1; off < 1024; off <<= 1) {
        int v = (t >= off) ? sh[t - off] : 0;
        __syncthreads();
        sh[t] += v;
        __syncthreads();
    }
    partial[t] = (t == 0) ? 0 : sh[t - 1];  // exclusive
}

__global__ void scan3_kernel(const int* __restrict__ cnt, const int* __restrict__ partial,
                             int* __restrict__ offs, int n, int C, int E) {
    int t = blockIdx.x * 256 + threadIdx.x;
    int run = partial[t];
    int base = t * C;
    for (int i = 0; i < C; ++i) {
        int idx = base + i;
        if (idx < n) {
            offs[idx] = run;
            run += cnt[idx];
        }
    }
    if (t == 0) offs[n] = E;
}

__global__ void inv_kernel(const int* __restrict__ cnt, float* __restrict__ inv, int n) {
    int i = blockIdx.x * 256 + threadIdx.x;
    if (i < n) inv[i] = 1.0f / (float)max(cnt[i], 1);
}

__global__ void fill_kernel(const int* __restrict__ src32, const int* __restrict__ dst32,
                            const int* __restrict__ offs, int* __restrict__ cursor,
                            int* __restrict__ sorted, int E) {
    int i = blockIdx.x * 256 + threadIdx.x;
    if (i >= E) return;
    int d = dst32[i];
    int p = offs[d] + atomicAdd(&cursor[d], 1);
    sorted[p] = src32[i];
}

// fp32 -> bf16, vectorized x4
__global__ void cvt_bf16_kernel(const float* __restrict__ x, unsigned short* __restrict__ xb,
                                int n4) {
    int i = blockIdx.x * 256 + threadIdx.x;
    if (i >= n4) return;
    float4 v = *(const float4*)(x + (size_t)i * 4);
    uint2 o;
    o.x = (unsigned int)f2bf(v.x) | ((unsigned int)f2bf(v.y) << 16);
    o.y = (unsigned int)f2bf(v.z) | ((unsigned int)f2bf(v.w) << 16);
    *(uint2*)(xb + (size_t)i * 4) = o;
}

// ---------------------------------------------------------------------------
// Layer-0 aggregation: 128-dim row-major gather, row-major out [Mpad][128].
// One wave per node, 4 edges unrolled.
// ---------------------------------------------------------------------------
__global__ void __launch_bounds__(256) agg128_kernel(
    const unsigned short* __restrict__ X, const int* __restrict__ srt,
    const int* __restrict__ offs, const float* __restrict__ invc,
    unsigned short* __restrict__ out, int nNodes) {
    int node = blockIdx.x * 4 + (threadIdx.x >> 6);
    if (node >= nNodes) return;
    int lane = threadIdx.x & 63;
    const unsigned short* xp = X + (size_t)lane * 2;
    int beg = offs[node], end = offs[node + 1];
    float sc = invc[node];
    float a0 = 0.f, a1 = 0.f;
    int e = beg;
    for (; e + 4 <= end; e += 4) {
        int s0 = srt[e], s1 = srt[e + 1], s2 = srt[e + 2], s3 = srt[e + 3];
        unsigned int v0 = *(const unsigned int*)(xp + (size_t)s0 * 128);
        unsigned int v1 = *(const unsigned int*)(xp + (size_t)s1 * 128);
        unsigned int v2 = *(const unsigned int*)(xp + (size_t)s2 * 128);
        unsigned int v3 = *(const unsigned int*)(xp + (size_t)s3 * 128);
        a0 += bf2f(v0 & 0xffffu) + bf2f(v1 & 0xffffu) + bf2f(v2 & 0xffffu) + bf2f(v3 & 0xffffu);
        a1 += bf2f(v0 >> 16) + bf2f(v1 >> 16) + bf2f(v2 >> 16) + bf2f(v3 >> 16);
    }
    for (; e < end; ++e) {
        unsigned int v = *(const unsigned int*)(xp + (size_t)srt[e] * 128);
        a0 += bf2f(v & 0xffffu);
        a1 += bf2f(v >> 16);
    }
    unsigned int o = (unsigned int)f2bf(a0 * sc) | ((unsigned int)f2bf(a1 * sc) << 16);
    *(unsigned int*)(out + (size_t)node * 128 + lane * 2) = o;
}

// ---------------------------------------------------------------------------
// Fused aggregation + add + relu (after-GEMM, associativity restructure):
// out[dst] = relu( inv[dst] * sum_{e} P[srt[e]] + Q[dst] ), all row-major.
// D=512: lane covers 8 bf16 (16B). One wave per node, 4 edges unrolled.
// ---------------------------------------------------------------------------
__global__ void __launch_bounds__(256) aggfuse512_kernel(
    const unsigned short* __restrict__ P, const unsigned short* __restrict__ Q,
    const int* __restrict__ srt, const int* __restrict__ offs,
    const float* __restrict__ invc, unsigned short* __restrict__ out, int nNodes) {
    int node = blockIdx.x * 4 + (threadIdx.x >> 6);
    if (node >= nNodes) return;
    int lane = threadIdx.x & 63;
    const unsigned short* pp = P + (size_t)lane * 8;
    int beg = offs[node], end = offs[node + 1];
    float sc = invc[node];
    float a0 = 0.f, a1 = 0.f, a2 = 0.f, a3 = 0.f, a4 = 0.f, a5 = 0.f, a6 = 0.f, a7 = 0.f;
#define ACC8(v)                                \
    do {                                       \
        a0 += bf2f((v).x & 0xffffu);           \
        a1 += bf2f((v).x >> 16);               \
        a2 += bf2f((v).y & 0xffffu);           \
        a3 += bf2f((v).y >> 16);               \
        a4 += bf2f((v).z & 0xffffu);           \
        a5 += bf2f((v).z >> 16);               \
        a6 += bf2f((v).w & 0xffffu);           \
        a7 += bf2f((v).w >> 16);               \
    } while (0)
    int e = beg;
    for (; e + 4 <= end; e += 4) {
        int s0 = srt[e], s1 = srt[e + 1], s2 = srt[e + 2], s3 = srt[e + 3];
        uint4 v0 = *(const uint4*)(pp + (size_t)s0 * 512);
        uint4 v1 = *(const uint4*)(pp + (size_t)s1 * 512);
        uint4 v2 = *(const uint4*)(pp + (size_t)s2 * 512);
        uint4 v3 = *(const uint4*)(pp + (size_t)s3 * 512);
        ACC8(v0); ACC8(v1); ACC8(v2); ACC8(v3);
    }
    for (; e < end; ++e) {
        uint4 v = *(const uint4*)(pp + (size_t)srt[e] * 512);
        ACC8(v);
    }
#undef ACC8
    uint4 q = *(const uint4*)(Q + (size_t)node * 512 + lane * 8);
    float q0 = bf2f(q.x & 0xffffu), q1 = bf2f(q.x >> 16);
    float q2 = bf2f(q.y & 0xffffu), q3 = bf2f(q.y >> 16);
    float q4 = bf2f(q.z & 0xffffu), q5 = bf2f(q.z >> 16);
    float q6 = bf2f(q.w & 0xffffu), q7 = bf2f(q.w >> 16);
    float r0 = fmaxf(a0 * sc + q0, 0.f), r1 = fmaxf(a1 * sc + q1, 0.f);
    float r2 = fmaxf(a2 * sc + q2, 0.f), r3 = fmaxf(a3 * sc + q3, 0.f);
    float r4 = fmaxf(a4 * sc + q4, 0.f), r5 = fmaxf(a5 * sc + q5, 0.f);
    float r6 = fmaxf(a6 * sc + q6, 0.f), r7 = fmaxf(a7 * sc + q7, 0.f);
    uint4 o;
    o.x = (unsigned int)f2bf(r0) | ((unsigned int)f2bf(r1) << 16);
    o.y = (unsigned int)f2bf(r2) | ((unsigned int)f2bf(r3) << 16);
    o.z = (unsigned int)f2bf(r4) | ((unsigned int)f2bf(r5) << 16);
    o.w = (unsigned int)f2bf(r6) | ((unsigned int)f2bf(r7) << 16);
    *(uint4*)(out + (size_t)node * 512 + lane * 8) = o;
}

// D=256 variant, fp32 Q and fp32 out (final layer, no relu).
__global__ void __launch_bounds__(256) aggfuse256_kernel(
    const unsigned short* __restrict__ P, const float* __restrict__ Q,
    const int* __restrict__ srt, const int* __restrict__ offs,
    const float* __restrict__ invc, float* __restrict__ out, int nNodes) {
    int node = blockIdx.x * 4 + (threadIdx.x >> 6);
    if (node >= nNodes) return;
    int lane = threadIdx.x & 63;
    const unsigned short* pp = P + (size_t)lane * 4;
    int beg = offs[node], end = offs[node + 1];
    float sc = invc[node];
    float a0 = 0.f, a1 = 0.f, a2 = 0.f, a3 = 0.f;
#define ACC4(v)                              \
    do {                                     \
        a0 += bf2f((v).x & 0xffffu);         \
        a1 += bf2f((v).x >> 16);             \
        a2 += bf2f((v).y & 0xffffu);         \
        a3 += bf2f((v).y >> 16);             \
    } while (0)
    int e = beg;
    for (; e + 4 <= end; e += 4) {
        int s0 = srt[e], s1 = srt[e + 1], s2 = srt[e + 2], s3 = srt[e + 3];
        uint2 v0 = *(const uint2*)(pp + (size_t)s0 * 256);
        uint2 v1 = *(const uint2*)(pp + (size_t)s1 * 256);
        uint2 v2 = *(const uint2*)(pp + (size_t)s2 * 256);
        uint2 v3 = *(const uint2*)(pp + (size_t)s3 * 256);
        ACC4(v0); ACC4(v1); ACC4(v2); ACC4(v3);
    }
    for (; e < end; ++e) {
        uint2 v = *(const uint2*)(pp + (size_t)srt[e] * 256);
        ACC4(v);
    }
#undef ACC4
    float4 q = *(const float4*)(Q + (size_t)node * 256 + lane * 4);
    float4 r = make_float4(a0 * sc + q.x, a1 * sc + q.y, a2 * sc + q.z, a3 * sc + q.w);
    *(float4*)(out + (size_t)node * 256 + lane * 4) = r;
}

// ---------------------------------------------------------------------------
// MFMA SAGE GEMM (layer 0): C = relu( Aagg @ Wl^T + Aself @ Wr^T + bias )
// Row-major bf16 A [Mpad,K], W [N,K]. Tile 128(M) x 256(N), BK=32, 4 waves
// of 4x8 16x16x32 frags. bf16 row-major out. (round-4 kernel, proven 733 us)
// ---------------------------------------------------------------------------
__global__ void __launch_bounds__(256, 2) sage_gemm_mfma(
    const unsigned short* __restrict__ Aagg, const unsigned short* __restrict__ Aself,
    const unsigned short* __restrict__ Wlb, const unsigned short* __restrict__ Wrb,
    const float* __restrict__ bias, unsigned short* __restrict__ Cout,
    int M, int N, int K) {
    __shared__ __attribute__((aligned(16))) unsigned short As[128 * 32];  //  8 KB
    __shared__ __attribute__((aligned(16))) unsigned short Bs[256 * 32];  // 16 KB
    const int tid = threadIdx.x;
    const int lane = tid & 63;
    const int wave = tid >> 6;
    const int wm = wave >> 1, wn = wave & 1;          // 2x2 wave grid
    const int m0 = blockIdx.y * 128, n0 = blockIdx.x * 256;

    f32x4 acc[4][8];
#pragma unroll
    for (int i = 0; i < 4; ++i)
#pragma unroll
        for (int j = 0; j < 8; ++j) acc[i][j] = (f32x4){0.f, 0.f, 0.f, 0.f};

    const int srow = wave * 16 + (lane >> 2);
    const int kE = (lane & 3) * 8;
    const int frow = lane & 15;
    const int kk = (lane >> 4) * 8;

    for (int pass = 0; pass < 2; ++pass) {
        const unsigned short* A = pass ? Aself : Aagg;
        const unsigned short* W = pass ? Wrb : Wlb;
        for (int k0 = 0; k0 < K; k0 += 32) {
            __syncthreads();
            GLD_LDS(A + (size_t)(m0 + 0 * 64 + srow) * K + k0 + kE, &As[0 * 2048 + wave * 512]);
            GLD_LDS(A + (size_t)(m0 + 1 * 64 + srow) * K + k0 + kE, &As[1 * 2048 + wave * 512]);
            GLD_LDS(W + (size_t)(n0 + 0 * 64 + srow) * K + k0 + kE, &Bs[0 * 2048 + wave * 512]);
            GLD_LDS(W + (size_t)(n0 + 1 * 64 + srow) * K + k0 + kE, &Bs[1 * 2048 + wave * 512]);
            GLD_LDS(W + (size_t)(n0 + 2 * 64 + srow) * K + k0 + kE, &Bs[2 * 2048 + wave * 512]);
            GLD_LDS(W + (size_t)(n0 + 3 * 64 + srow) * K + k0 + kE, &Bs[3 * 2048 + wave * 512]);
            __syncthreads();
            bf16x8 af[4], bfr[8];
#pragma unroll
            for (int t = 0; t < 4; ++t)
                af[t] = *(const bf16x8*)&As[(wm * 64 + t * 16 + frow) * 32 + kk];
#pragma unroll
            for (int t = 0; t < 8; ++t)
                bfr[t] = *(const bf16x8*)&Bs[(wn * 128 + t * 16 + frow) * 32 + kk];
#pragma unroll
            for (int i = 0; i < 4; ++i)
#pragma unroll
                for (int j = 0; j < 8; ++j)
                    acc[i][j] = __builtin_amdgcn_mfma_f32_16x16x32_bf16(
                        af[i], bfr[j], acc[i][j], 0, 0, 0);
        }
    }

    const int col = lane & 15;
    const int rgrp = (lane >> 4) * 4;
#pragma unroll
    for (int j = 0; j < 8; ++j) {
        int n = n0 + wn * 128 + j * 16 + col;
        float bv = bias[n];
#pragma unroll
        for (int i = 0; i < 4; ++i) {
            int mBase = m0 + wm * 64 + i * 16 + rgrp;
#pragma unroll
            for (int r = 0; r < 4; ++r) {
                int m = mBase + r;
                if (m >= M) continue;
                float v = fmaxf(acc[i][j][r] + bv, 0.f);
                Cout[(size_t)m * N + n] = f2bf(v);
            }
        }
    }
}

// ---------------------------------------------------------------------------
// Dual-output MFMA GEMM (layers 1-2, associativity restructure):
//   P = A @ Wl^T          (bf16, gathered afterwards - NO bias, NO relu)
//   Q = A @ Wr^T + bias   (bf16 or fp32)
// grid.x covers 2N in 256-col blocks: first N/256 blocks -> Wl/P, rest -> Wr/Q.
// A staged ONCE per k-step (half the staging of the 2-pass kernel).
// ---------------------------------------------------------------------------
__global__ void __launch_bounds__(256, 2) dual_gemm_mfma(
    const unsigned short* __restrict__ A,
    const unsigned short* __restrict__ Wlb, const unsigned short* __restrict__ Wrb,
    const float* __restrict__ bias, unsigned short* __restrict__ P,
    void* __restrict__ Q, int M, int N, int K, int q_fp32) {
    __shared__ __attribute__((aligned(16))) unsigned short As[128 * 32];  //  8 KB
    __shared__ __attribute__((aligned(16))) unsigned short Bs[256 * 32];  // 16 KB
    const int tid = threadIdx.x;
    const int lane = tid & 63;
    const int wave = tid >> 6;
    const int wm = wave >> 1, wn = wave & 1;
    const int m0 = blockIdx.y * 128;
    const int n0s = blockIdx.x * 256;          // in [0, 2N)
    const int isQ = n0s >= N;
    const int n0 = isQ ? n0s - N : n0s;
    const unsigned short* W = isQ ? Wrb : Wlb;

    f32x4 acc[4][8];
#pragma unroll
    for (int i = 0; i < 4; ++i)
#pragma unroll
        for (int j = 0; j < 8; ++j) acc[i][j] = (f32x4){0.f, 0.f, 0.f, 0.f};

    const int srow = wave * 16 + (lane >> 2);
    const int kE = (lane & 3) * 8;
    const int frow = lane & 15;
    const int kk = (lane >> 4) * 8;

    for (int k0 = 0; k0 < K; k0 += 32) {
        __syncthreads();
        GLD_LDS(A + (size_t)(m0 + 0 * 64 + srow) * K + k0 + kE, &As[0 * 2048 + wave * 512]);
        GLD_LDS(A + (size_t)(m0 + 1 * 64 + srow) * K + k0 + kE, &As[1 * 2048 + wave * 512]);
        GLD_LDS(W + (size_t)(n0 + 0 * 64 + srow) * K + k0 + kE, &Bs[0 * 2048 + wave * 512]);
        GLD_LDS(W + (size_t)(n0 + 1 * 64 + srow) * K + k0 + kE, &Bs[1 * 2048 + wave * 512]);
        GLD_LDS(W + (size_t)(n0 + 2 * 64 + srow) * K + k0 + kE, &Bs[2 * 2048 + wave * 512]);
        GLD_LDS(W + (size_t)(n0 + 3 * 64 + srow) * K + k0 + kE, &Bs[3 * 2048 + wave * 512]);
        __syncthreads();
        bf16x8 af[4], bfr[8];
#pragma unroll
        for (int t = 0; t < 4; ++t)
            af[t] = *(const bf16x8*)&As[(wm * 64 + t * 16 + frow) * 32 + kk];
#pragma unroll
        for (int t = 0; t < 8; ++t)
            bfr[t] = *(const bf16x8*)&Bs[(wn * 128 + t * 16 + frow) * 32 + kk];
#pragma unroll
        for (int i = 0; i < 4; ++i)
#pragma unroll
            for (int j = 0; j < 8; ++j)
                acc[i][j] = __builtin_amdgcn_mfma_f32_16x16x32_bf16(
                    af[i], bfr[j], acc[i][j], 0, 0, 0);
    }

    const int col = lane & 15;
    const int rgrp = (lane >> 4) * 4;
#pragma unroll
    for (int j = 0; j < 8; ++j) {
        int n = n0 + wn * 128 + j * 16 + col;
        float bv = isQ ? bias[n] : 0.f;
#pragma unroll
        for (int i = 0; i < 4; ++i) {
            int mBase = m0 + wm * 64 + i * 16 + rgrp;
#pragma unroll
            for (int r = 0; r < 4; ++r) {
                int m = mBase + r;
                if (m >= M) continue;
                float v = acc[i][j][r] + bv;
                if (!isQ)
                    P[(size_t)m * N + n] = f2bf(v);
                else if (q_fp32)
                    ((float*)Q)[(size_t)m * N + n] = v;
                else
                    ((unsigned short*)Q)[(size_t)m * N + n] = f2bf(v);
            }
        }
    }
}

// ---------------------------------------------------------------------------
extern "C" void kernel_launch(void* const* d_in, const int* in_sizes, int n_in,
                              void* d_out, int out_size, void* d_ws, size_t ws_size,
                              hipStream_t stream) {
    const float* x   = (const float*)d_in[0];
    const int*   e   = (const int*)d_in[1];
    const float* Wl0 = (const float*)d_in[2];
    const float* bl0 = (const float*)d_in[3];
    const float* Wr0 = (const float*)d_in[4];
    const float* Wl1 = (const float*)d_in[5];
    const float* bl1 = (const float*)d_in[6];
    const float* Wr1 = (const float*)d_in[7];
    const float* Wl2 = (const float*)d_in[8];
    const float* bl2 = (const float*)d_in[9];
    const float* Wr2 = (const float*)d_in[10];
    float* out = (float*)d_out;

    const int N = in_sizes[0] / 128;           // 50000 nodes
    const int E = in_sizes[1] / 2;             // 800000 edges
    const int Mpad = ((N + 127) / 128) * 128;  // 50048: GEMM staging never OOB

    char* ws = (char*)d_ws;
    size_t off = 0;
    auto alloc = [&](size_t bytes) { size_t o = off; off = align_up(off + bytes, 512); return o; };

    size_t o_nz     = alloc(4);
    size_t o_cnt    = alloc((size_t)N * 4);
    size_t o_cursor = alloc((size_t)N * 4);
    size_t zero_end = off;                       // [0, zero_end) zeroed each call
    size_t o_part   = alloc(1024 * 4);
    size_t o_offs   = alloc((size_t)(N + 1) * 4);
    size_t o_inv    = alloc((size_t)N * 4);
    size_t o_src    = alloc((size_t)E * 4);
    size_t o_dst    = alloc((size_t)E * 4);
    size_t o_sort   = alloc((size_t)E * 4);
    size_t o_xb     = alloc((size_t)Mpad * 128 * 2);   // bf16 x row-major
    size_t o_aggx   = alloc((size_t)Mpad * 128 * 2);   // bf16 agg(x)
    size_t o_h      = alloc((size_t)Mpad * 512 * 2);   // h0, then h1 (disjoint lifetimes)
    size_t o_P      = alloc((size_t)Mpad * 512 * 2);   // P1 (512), then P2 (256)
    size_t o_Q      = alloc((size_t)Mpad * 512 * 2);   // Q1 bf16 (512), then Q2 fp32 (256)
    size_t o_wl0    = alloc((size_t)512 * 128 * 2);
    size_t o_wr0    = alloc((size_t)512 * 128 * 2);
    size_t o_wl1    = alloc((size_t)512 * 512 * 2);
    size_t o_wr1    = alloc((size_t)512 * 512 * 2);
    size_t o_wl2    = alloc((size_t)256 * 512 * 2);
    size_t o_wr2    = alloc((size_t)256 * 512 * 2);
    (void)ws_size; (void)n_in; (void)out_size;

    int*            nz     = (int*)(ws + o_nz);
    int*            cnt    = (int*)(ws + o_cnt);
    int*            cursor = (int*)(ws + o_cursor);
    int*            part   = (int*)(ws + o_part);
    int*            offs   = (int*)(ws + o_offs);
    float*          inv    = (float*)(ws + o_inv);
    int*            src32  = (int*)(ws + o_src);
    int*            dst32  = (int*)(ws + o_dst);
    int*            sorted = (int*)(ws + o_sort);
    unsigned short* xb     = (unsigned short*)(ws + o_xb);
    unsigned short* aggx   = (unsigned short*)(ws + o_aggx);
    unsigned short* hbuf   = (unsigned short*)(ws + o_h);
    unsigned short* Pbuf   = (unsigned short*)(ws + o_P);
    unsigned short* Qbuf   = (unsigned short*)(ws + o_Q);   // bf16 view (layer 1)
    float*          Qf     = (float*)(ws + o_Q);            // fp32 view (layer 2)
    unsigned short* wl0b   = (unsigned short*)(ws + o_wl0);
    unsigned short* wr0b   = (unsigned short*)(ws + o_wr0);
    unsigned short* wl1b   = (unsigned short*)(ws + o_wl1);
    unsigned short* wr1b   = (unsigned short*)(ws + o_wr1);
    unsigned short* wl2b   = (unsigned short*)(ws + o_wl2);
    unsigned short* wr2b   = (unsigned short*)(ws + o_wr2);

    // zero nz/cnt/cursor (ws poisoned 0xAA before every call)
    int zn = (int)(zero_end / 4);
    zero_kernel<<<(zn + 255) / 256, 256, 0, stream>>>((int*)ws, zn);

    int eb = (E + 255) / 256;
    detect_kernel<<<1, 256, 0, stream>>>(e, nz, E);
    conv_count_kernel<<<eb, 256, 0, stream>>>(e, nz, src32, dst32, cnt, E);

    const int C = (N + 1023) / 1024;
    scan1_kernel<<<4, 256, 0, stream>>>(cnt, part, N, C);
    scan2_kernel<<<1, 1024, 0, stream>>>(part);
    scan3_kernel<<<4, 256, 0, stream>>>(cnt, part, offs, N, C, E);
    inv_kernel<<<(N + 255) / 256, 256, 0, stream>>>(cnt, inv, N);
    fill_kernel<<<eb, 256, 0, stream>>>(src32, dst32, offs, cursor, sorted, E);

    // conversions to bf16
    int n4 = N * 128 / 4;
    cvt_bf16_kernel<<<(n4 + 255) / 256, 256, 0, stream>>>(x, xb, n4);
    cvt_bf16_kernel<<<(512 * 128 / 4 + 255) / 256, 256, 0, stream>>>(Wl0, wl0b, 512 * 128 / 4);
    cvt_bf16_kernel<<<(512 * 128 / 4 + 255) / 256, 256, 0, stream>>>(Wr0, wr0b, 512 * 128 / 4);
    cvt_bf16_kernel<<<(512 * 512 / 4 + 255) / 256, 256, 0, stream>>>(Wl1, wl1b, 512 * 512 / 4);
    cvt_bf16_kernel<<<(512 * 512 / 4 + 255) / 256, 256, 0, stream>>>(Wr1, wr1b, 512 * 512 / 4);
    cvt_bf16_kernel<<<(256 * 512 / 4 + 255) / 256, 256, 0, stream>>>(Wl2, wl2b, 256 * 512 / 4);
    cvt_bf16_kernel<<<(256 * 512 / 4 + 255) / 256, 256, 0, stream>>>(Wr2, wr2b, 256 * 512 / 4);

    const int aggBlocks = (N + 3) / 4;
    const int mBlocks = Mpad / 128;

    // Layer 0: agg-then-GEMM (aggregating 128-dim x is the cheap side).
    agg128_kernel<<<aggBlocks, 256, 0, stream>>>(xb, sorted, offs, inv, aggx, N);
    sage_gemm_mfma<<<dim3(2, mBlocks), 256, 0, stream>>>(
        aggx, xb, wl0b, wr0b, bl0, hbuf, N, 512, 128);

    // Layer 1: GEMM-then-agg (agg is linear): P1=h0@Wl1^T, Q1=h0@Wr1^T+bl1;
    // h1 = relu(inv*sum P1[src] + Q1)
    dual_gemm_mfma<<<dim3(4, mBlocks), 256, 0, stream>>>(
        hbuf, wl1b, wr1b, bl1, Pbuf, Qbuf, N, 512, 512, 0);
    aggfuse512_kernel<<<aggBlocks, 256, 0, stream>>>(
        Pbuf, Qbuf, sorted, offs, inv, hbuf, N);

    // Layer 2: GEMM-then-agg at 256-dim (gather halves: 819 -> 410 MB);
    // out = inv*sum P2[src] + Q2 (fp32, no relu)
    dual_gemm_mfma<<<dim3(2, mBlocks), 256, 0, stream>>>(
        hbuf, wl2b, wr2b, bl2, Pbuf, (void*)Qf, N, 256, 512, 1);
    aggfuse256_kernel<<<aggBlocks, 256, 0, stream>>>(
        Pbuf, Qf, sorted, offs, inv, out, N);
}

// Round 8
// 651.102 us; speedup vs baseline: 1.1790x; 1.1469x over previous
//
#include <hip/hip_runtime.h>
#include <hip/hip_bf16.h>
#include <cstdint>
#include <cstddef>

static inline size_t align_up(size_t x, size_t a) { return (x + a - 1) & ~(a - 1); }

typedef __attribute__((ext_vector_type(4))) float f32x4;
typedef __attribute__((ext_vector_type(8))) short bf16x8;

__device__ inline float bf2f(unsigned int u16) {        // low 16 bits hold bf16
    return __uint_as_float(u16 << 16);
}
__device__ inline unsigned short f2bf(float f) {        // round-to-nearest-even
    unsigned int u = __float_as_uint(f);
    u = (u + 0x7fffu + ((u >> 16) & 1u)) >> 16;
    return (unsigned short)u;
}

#define GLD_LDS(gp, lp) \
    __builtin_amdgcn_global_load_lds( \
        (const __attribute__((address_space(1))) unsigned int*)(gp), \
        (__attribute__((address_space(3))) unsigned int*)(lp), 16, 0, 0)

// ---------------------------------------------------------------------------
__global__ void zero_kernel(int* __restrict__ p, int n) {
    int i = blockIdx.x * 256 + threadIdx.x;
    if (i < n) p[i] = 0;
}

// Edge-encoding detection, single block, sampled, no atomics.
__global__ void detect_kernel(const int* __restrict__ e, int* __restrict__ nz, int E) {
    int t = threadIdx.x;  // 0..255, one block
    long long stride = (long long)E / 4096;
    if (stride < 1) stride = 1;
    int any = 0;
    for (int k = 0; k < 16; ++k) {
        long long idx = (long long)(t * 16 + k) * stride;
        if (idx < E && e[2 * idx + 1] != 0) any = 1;
    }
    if (any) nz[0] = 1;  // same-value race is benign
}

__global__ void conv_count_kernel(const int* __restrict__ eraw, const int* __restrict__ nz,
                                  int* __restrict__ src32, int* __restrict__ dst32,
                                  int* __restrict__ cnt, int E) {
    int i = blockIdx.x * blockDim.x + threadIdx.x;
    if (i >= E) return;
    int s, d;
    if (*nz == 0) {  // int64 storage
        const long long* e64 = (const long long*)eraw;
        s = (int)e64[i];
        d = (int)e64[i + E];
    } else {         // int32 storage
        s = eraw[i];
        d = eraw[i + E];
    }
    src32[i] = s;
    dst32[i] = d;
    atomicAdd(&cnt[d], 1);
}

// 3-kernel exclusive scan over cnt[0..n) -> offs[0..n]
__global__ void scan1_kernel(const int* __restrict__ cnt, int* __restrict__ partial,
                             int n, int C) {
    int t = blockIdx.x * 256 + threadIdx.x;  // 0..1023
    int s = 0;
    int base = t * C;
    for (int i = 0; i < C; ++i) {
        int idx = base + i;
        if (idx < n) s += cnt[idx];
    }
    partial[t] = s;
}

__global__ void __launch_bounds__(1024) scan2_kernel(int* __restrict__ partial) {
    __shared__ int sh[1024];
    int t = threadIdx.x;
    sh[t] = partial[t];
    __syncthreads();
    for (int off = 1; off < 1024; off <<= 1) {
        int v = (t >= off) ? sh[t - off] : 0;
        __syncthreads();
        sh[t] += v;
        __syncthreads();
    }
    partial[t] = (t == 0) ? 0 : sh[t - 1];  // exclusive
}

__global__ void scan3_kernel(const int* __restrict__ cnt, const int* __restrict__ partial,
                             int* __restrict__ offs, int n, int C, int E) {
    int t = blockIdx.x * 256 + threadIdx.x;
    int run = partial[t];
    int base = t * C;
    for (int i = 0; i < C; ++i) {
        int idx = base + i;
        if (idx < n) {
            offs[idx] = run;
            run += cnt[idx];
        }
    }
    if (t == 0) offs[n] = E;
}

__global__ void inv_kernel(const int* __restrict__ cnt, float* __restrict__ inv, int n) {
    int i = blockIdx.x * 256 + threadIdx.x;
    if (i < n) inv[i] = 1.0f / (float)max(cnt[i], 1);
}

__global__ void fill_kernel(const int* __restrict__ src32, const int* __restrict__ dst32,
                            const int* __restrict__ offs, int* __restrict__ cursor,
                            int* __restrict__ sorted, int E) {
    int i = blockIdx.x * 256 + threadIdx.x;
    if (i >= E) return;
    int d = dst32[i];
    int p = offs[d] + atomicAdd(&cursor[d], 1);
    sorted[p] = src32[i];
}

// fp32 -> bf16, vectorized x4
__global__ void cvt_bf16_kernel(const float* __restrict__ x, unsigned short* __restrict__ xb,
                                int n4) {
    int i = blockIdx.x * 256 + threadIdx.x;
    if (i >= n4) return;
    float4 v = *(const float4*)(x + (size_t)i * 4);
    uint2 o;
    o.x = (unsigned int)f2bf(v.x) | ((unsigned int)f2bf(v.y) << 16);
    o.y = (unsigned int)f2bf(v.z) | ((unsigned int)f2bf(v.w) << 16);
    *(uint2*)(xb + (size_t)i * 4) = o;
}

// ---------------------------------------------------------------------------
// Layer-0 aggregation: 128-dim row-major gather, row-major out. 8-edge unroll.
// ---------------------------------------------------------------------------
__global__ void __launch_bounds__(256) agg128_kernel(
    const unsigned short* __restrict__ X, const int* __restrict__ srt,
    const int* __restrict__ offs, const float* __restrict__ invc,
    unsigned short* __restrict__ out, int nNodes) {
    int node = blockIdx.x * 4 + (threadIdx.x >> 6);
    if (node >= nNodes) return;
    int lane = threadIdx.x & 63;
    const unsigned short* xp = X + (size_t)lane * 2;
    int beg = offs[node], end = offs[node + 1];
    float sc = invc[node];
    float a0 = 0.f, a1 = 0.f;
    int e = beg;
    for (; e + 8 <= end; e += 8) {
        unsigned int v[8];
#pragma unroll
        for (int u = 0; u < 8; ++u)
            v[u] = *(const unsigned int*)(xp + (size_t)srt[e + u] * 128);
#pragma unroll
        for (int u = 0; u < 8; ++u) {
            a0 += bf2f(v[u] & 0xffffu);
            a1 += bf2f(v[u] >> 16);
        }
    }
    for (; e < end; ++e) {
        unsigned int v = *(const unsigned int*)(xp + (size_t)srt[e] * 128);
        a0 += bf2f(v & 0xffffu);
        a1 += bf2f(v >> 16);
    }
    unsigned int o = (unsigned int)f2bf(a0 * sc) | ((unsigned int)f2bf(a1 * sc) << 16);
    *(unsigned int*)(out + (size_t)node * 128 + lane * 2) = o;
}

// ---------------------------------------------------------------------------
// Fused aggregation + add + relu: out[dst] = relu(inv*sum P[src] + Q[dst]).
// D=512, 8-edge unroll, one wave per node.
// ---------------------------------------------------------------------------
__global__ void __launch_bounds__(256) aggfuse512_kernel(
    const unsigned short* __restrict__ P, const unsigned short* __restrict__ Q,
    const int* __restrict__ srt, const int* __restrict__ offs,
    const float* __restrict__ invc, unsigned short* __restrict__ out, int nNodes) {
    int node = blockIdx.x * 4 + (threadIdx.x >> 6);
    if (node >= nNodes) return;
    int lane = threadIdx.x & 63;
    const unsigned short* pp = P + (size_t)lane * 8;
    int beg = offs[node], end = offs[node + 1];
    float sc = invc[node];
    float a0 = 0.f, a1 = 0.f, a2 = 0.f, a3 = 0.f, a4 = 0.f, a5 = 0.f, a6 = 0.f, a7 = 0.f;
#define ACC8(v)                                \
    do {                                       \
        a0 += bf2f((v).x & 0xffffu);           \
        a1 += bf2f((v).x >> 16);               \
        a2 += bf2f((v).y & 0xffffu);           \
        a3 += bf2f((v).y >> 16);               \
        a4 += bf2f((v).z & 0xffffu);           \
        a5 += bf2f((v).z >> 16);               \
        a6 += bf2f((v).w & 0xffffu);           \
        a7 += bf2f((v).w >> 16);               \
    } while (0)
    int e = beg;
    for (; e + 8 <= end; e += 8) {
        uint4 v[8];
#pragma unroll
        for (int u = 0; u < 8; ++u)
            v[u] = *(const uint4*)(pp + (size_t)srt[e + u] * 512);
#pragma unroll
        for (int u = 0; u < 8; ++u) ACC8(v[u]);
    }
    for (; e < end; ++e) {
        uint4 v = *(const uint4*)(pp + (size_t)srt[e] * 512);
        ACC8(v);
    }
#undef ACC8
    uint4 q = *(const uint4*)(Q + (size_t)node * 512 + lane * 8);
    float r0 = fmaxf(a0 * sc + bf2f(q.x & 0xffffu), 0.f);
    float r1 = fmaxf(a1 * sc + bf2f(q.x >> 16), 0.f);
    float r2 = fmaxf(a2 * sc + bf2f(q.y & 0xffffu), 0.f);
    float r3 = fmaxf(a3 * sc + bf2f(q.y >> 16), 0.f);
    float r4 = fmaxf(a4 * sc + bf2f(q.z & 0xffffu), 0.f);
    float r5 = fmaxf(a5 * sc + bf2f(q.z >> 16), 0.f);
    float r6 = fmaxf(a6 * sc + bf2f(q.w & 0xffffu), 0.f);
    float r7 = fmaxf(a7 * sc + bf2f(q.w >> 16), 0.f);
    uint4 o;
    o.x = (unsigned int)f2bf(r0) | ((unsigned int)f2bf(r1) << 16);
    o.y = (unsigned int)f2bf(r2) | ((unsigned int)f2bf(r3) << 16);
    o.z = (unsigned int)f2bf(r4) | ((unsigned int)f2bf(r5) << 16);
    o.w = (unsigned int)f2bf(r6) | ((unsigned int)f2bf(r7) << 16);
    *(uint4*)(out + (size_t)node * 512 + lane * 8) = o;
}

// D=256 variant, fp32 Q and fp32 out (final layer, no relu). 8-edge unroll.
__global__ void __launch_bounds__(256) aggfuse256_kernel(
    const unsigned short* __restrict__ P, const float* __restrict__ Q,
    const int* __restrict__ srt, const int* __restrict__ offs,
    const float* __restrict__ invc, float* __restrict__ out, int nNodes) {
    int node = blockIdx.x * 4 + (threadIdx.x >> 6);
    if (node >= nNodes) return;
    int lane = threadIdx.x & 63;
    const unsigned short* pp = P + (size_t)lane * 4;
    int beg = offs[node], end = offs[node + 1];
    float sc = invc[node];
    float a0 = 0.f, a1 = 0.f, a2 = 0.f, a3 = 0.f;
#define ACC4(v)                              \
    do {                                     \
        a0 += bf2f((v).x & 0xffffu);         \
        a1 += bf2f((v).x >> 16);             \
        a2 += bf2f((v).y & 0xffffu);         \
        a3 += bf2f((v).y >> 16);             \
    } while (0)
    int e = beg;
    for (; e + 8 <= end; e += 8) {
        uint2 v[8];
#pragma unroll
        for (int u = 0; u < 8; ++u)
            v[u] = *(const uint2*)(pp + (size_t)srt[e + u] * 256);
#pragma unroll
        for (int u = 0; u < 8; ++u) ACC4(v[u]);
    }
    for (; e < end; ++e) {
        uint2 v = *(const uint2*)(pp + (size_t)srt[e] * 256);
        ACC4(v);
    }
#undef ACC4
    float4 q = *(const float4*)(Q + (size_t)node * 256 + lane * 4);
    float4 r = make_float4(a0 * sc + q.x, a1 * sc + q.y, a2 * sc + q.z, a3 * sc + q.w);
    *(float4*)(out + (size_t)node * 256 + lane * 4) = r;
}

// ---------------------------------------------------------------------------
// Coalesced bf16 epilogue (round-7 counters: scalar bf16 stores doubled HBM
// writes, 202 vs 102 MB). Per wave: stage the 16x128 sub-tile column-major in
// LDS (stride 18 shorts: b32-aligned, <=4-way conflicts), read back row-major,
// store uint4 (8 bf16) -> 256 B contiguous per 16-lane group.
// ---------------------------------------------------------------------------
__device__ __forceinline__ void epilogue_bf16(
    f32x4 (&acc)[4][8], const float* bvj, int relu,
    unsigned short* smem, int wave, int lane,
    unsigned short* Cout, int m0, int n0, int wm, int wn, int M, int N) {
    unsigned short* stg = smem + wave * 2304;  // 128 cols * 18 shorts
    const int colc = lane & 15;
    const int rgrp = (lane >> 4) * 4;
    for (int i = 0; i < 4; ++i) {
        __syncthreads();
#pragma unroll
        for (int j = 0; j < 8; ++j) {
            float v0 = acc[i][j][0] + bvj[j];
            float v1 = acc[i][j][1] + bvj[j];
            float v2 = acc[i][j][2] + bvj[j];
            float v3 = acc[i][j][3] + bvj[j];
            if (relu) {
                v0 = fmaxf(v0, 0.f); v1 = fmaxf(v1, 0.f);
                v2 = fmaxf(v2, 0.f); v3 = fmaxf(v3, 0.f);
            }
            int c = j * 16 + colc;
            *(unsigned int*)&stg[c * 18 + rgrp] =
                (unsigned int)f2bf(v0) | ((unsigned int)f2bf(v1) << 16);
            *(unsigned int*)&stg[c * 18 + rgrp + 2] =
                (unsigned int)f2bf(v2) | ((unsigned int)f2bf(v3) << 16);
        }
        __syncthreads();
#pragma unroll
        for (int p = 0; p < 2; ++p) {
            int colg = lane & 15;                  // 8-col group
            int rp = p * 4 + (lane >> 4);          // row pair 0..7
            unsigned int w[8];
#pragma unroll
            for (int t = 0; t < 8; ++t)
                w[t] = *(const unsigned int*)&stg[(colg * 8 + t) * 18 + rp * 2];
            uint4 lo, hi;
            lo.x = (w[0] & 0xffffu) | (w[1] << 16);
            lo.y = (w[2] & 0xffffu) | (w[3] << 16);
            lo.z = (w[4] & 0xffffu) | (w[5] << 16);
            lo.w = (w[6] & 0xffffu) | (w[7] << 16);
            hi.x = (w[0] >> 16) | (w[1] & 0xffff0000u);
            hi.y = (w[2] >> 16) | (w[3] & 0xffff0000u);
            hi.z = (w[4] >> 16) | (w[5] & 0xffff0000u);
            hi.w = (w[6] >> 16) | (w[7] & 0xffff0000u);
            int mlo = m0 + wm * 64 + i * 16 + rp * 2;
            int n = n0 + wn * 128 + colg * 8;
            if (mlo < M)     *(uint4*)&Cout[(size_t)mlo * N + n] = lo;
            if (mlo + 1 < M) *(uint4*)&Cout[(size_t)(mlo + 1) * N + n] = hi;
        }
    }
}

// ---------------------------------------------------------------------------
// MFMA SAGE GEMM (layer 0): C = relu( Aagg @ Wl^T + Aself @ Wr^T + bias )
// Tile 128x256, BK=32, 4 waves of 4x8 frags. Coalesced bf16 epilogue.
// ---------------------------------------------------------------------------
__global__ void __launch_bounds__(256, 2) sage_gemm_mfma(
    const unsigned short* __restrict__ Aagg, const unsigned short* __restrict__ Aself,
    const unsigned short* __restrict__ Wlb, const unsigned short* __restrict__ Wrb,
    const float* __restrict__ bias, unsigned short* __restrict__ Cout,
    int M, int N, int K) {
    __shared__ __attribute__((aligned(16))) unsigned short smem[12288];  // 24 KB
    unsigned short* As = smem;            // 128*32
    unsigned short* Bs = smem + 4096;     // 256*32
    const int tid = threadIdx.x;
    const int lane = tid & 63;
    const int wave = tid >> 6;
    const int wm = wave >> 1, wn = wave & 1;
    const int m0 = blockIdx.y * 128, n0 = blockIdx.x * 256;

    f32x4 acc[4][8];
#pragma unroll
    for (int i = 0; i < 4; ++i)
#pragma unroll
        for (int j = 0; j < 8; ++j) acc[i][j] = (f32x4){0.f, 0.f, 0.f, 0.f};

    const int srow = wave * 16 + (lane >> 2);
    const int kE = (lane & 3) * 8;
    const int frow = lane & 15;
    const int kk = (lane >> 4) * 8;

    for (int pass = 0; pass < 2; ++pass) {
        const unsigned short* A = pass ? Aself : Aagg;
        const unsigned short* W = pass ? Wrb : Wlb;
        for (int k0 = 0; k0 < K; k0 += 32) {
            __syncthreads();
            GLD_LDS(A + (size_t)(m0 + 0 * 64 + srow) * K + k0 + kE, &As[0 * 2048 + wave * 512]);
            GLD_LDS(A + (size_t)(m0 + 1 * 64 + srow) * K + k0 + kE, &As[1 * 2048 + wave * 512]);
            GLD_LDS(W + (size_t)(n0 + 0 * 64 + srow) * K + k0 + kE, &Bs[0 * 2048 + wave * 512]);
            GLD_LDS(W + (size_t)(n0 + 1 * 64 + srow) * K + k0 + kE, &Bs[1 * 2048 + wave * 512]);
            GLD_LDS(W + (size_t)(n0 + 2 * 64 + srow) * K + k0 + kE, &Bs[2 * 2048 + wave * 512]);
            GLD_LDS(W + (size_t)(n0 + 3 * 64 + srow) * K + k0 + kE, &Bs[3 * 2048 + wave * 512]);
            __syncthreads();
            bf16x8 af[4], bfr[8];
#pragma unroll
            for (int t = 0; t < 4; ++t)
                af[t] = *(const bf16x8*)&As[(wm * 64 + t * 16 + frow) * 32 + kk];
#pragma unroll
            for (int t = 0; t < 8; ++t)
                bfr[t] = *(const bf16x8*)&Bs[(wn * 128 + t * 16 + frow) * 32 + kk];
#pragma unroll
            for (int i = 0; i < 4; ++i)
#pragma unroll
                for (int j = 0; j < 8; ++j)
                    acc[i][j] = __builtin_amdgcn_mfma_f32_16x16x32_bf16(
                        af[i], bfr[j], acc[i][j], 0, 0, 0);
        }
    }

    float bvj[8];
#pragma unroll
    for (int j = 0; j < 8; ++j) bvj[j] = bias[n0 + wn * 128 + j * 16 + (lane & 15)];
    epilogue_bf16(acc, bvj, 1, smem, wave, lane, Cout, m0, n0, wm, wn, M, N);
}

// ---------------------------------------------------------------------------
// Dual-output MFMA GEMM (layers 1-2): P = A@Wl^T ; Q = A@Wr^T + bias.
// grid.x covers 2N in 256-col blocks (first half P, second half Q).
// bf16 outputs via coalesced epilogue; fp32 Q direct (already coalesced).
// ---------------------------------------------------------------------------
__global__ void __launch_bounds__(256, 2) dual_gemm_mfma(
    const unsigned short* __restrict__ A,
    const unsigned short* __restrict__ Wlb, const unsigned short* __restrict__ Wrb,
    const float* __restrict__ bias, unsigned short* __restrict__ P,
    void* __restrict__ Q, int M, int N, int K, int q_fp32) {
    __shared__ __attribute__((aligned(16))) unsigned short smem[12288];  // 24 KB
    unsigned short* As = smem;
    unsigned short* Bs = smem + 4096;
    const int tid = threadIdx.x;
    const int lane = tid & 63;
    const int wave = tid >> 6;
    const int wm = wave >> 1, wn = wave & 1;
    const int m0 = blockIdx.y * 128;
    const int n0s = blockIdx.x * 256;          // in [0, 2N)
    const int isQ = n0s >= N;
    const int n0 = isQ ? n0s - N : n0s;
    const unsigned short* W = isQ ? Wrb : Wlb;

    f32x4 acc[4][8];
#pragma unroll
    for (int i = 0; i < 4; ++i)
#pragma unroll
        for (int j = 0; j < 8; ++j) acc[i][j] = (f32x4){0.f, 0.f, 0.f, 0.f};

    const int srow = wave * 16 + (lane >> 2);
    const int kE = (lane & 3) * 8;
    const int frow = lane & 15;
    const int kk = (lane >> 4) * 8;

    for (int k0 = 0; k0 < K; k0 += 32) {
        __syncthreads();
        GLD_LDS(A + (size_t)(m0 + 0 * 64 + srow) * K + k0 + kE, &As[0 * 2048 + wave * 512]);
        GLD_LDS(A + (size_t)(m0 + 1 * 64 + srow) * K + k0 + kE, &As[1 * 2048 + wave * 512]);
        GLD_LDS(W + (size_t)(n0 + 0 * 64 + srow) * K + k0 + kE, &Bs[0 * 2048 + wave * 512]);
        GLD_LDS(W + (size_t)(n0 + 1 * 64 + srow) * K + k0 + kE, &Bs[1 * 2048 + wave * 512]);
        GLD_LDS(W + (size_t)(n0 + 2 * 64 + srow) * K + k0 + kE, &Bs[2 * 2048 + wave * 512]);
        GLD_LDS(W + (size_t)(n0 + 3 * 64 + srow) * K + k0 + kE, &Bs[3 * 2048 + wave * 512]);
        __syncthreads();
        bf16x8 af[4], bfr[8];
#pragma unroll
        for (int t = 0; t < 4; ++t)
            af[t] = *(const bf16x8*)&As[(wm * 64 + t * 16 + frow) * 32 + kk];
#pragma unroll
        for (int t = 0; t < 8; ++t)
            bfr[t] = *(const bf16x8*)&Bs[(wn * 128 + t * 16 + frow) * 32 + kk];
#pragma unroll
        for (int i = 0; i < 4; ++i)
#pragma unroll
            for (int j = 0; j < 8; ++j)
                acc[i][j] = __builtin_amdgcn_mfma_f32_16x16x32_bf16(
                    af[i], bfr[j], acc[i][j], 0, 0, 0);
    }

    if (!isQ || !q_fp32) {
        float bvj[8];
#pragma unroll
        for (int j = 0; j < 8; ++j)
            bvj[j] = isQ ? bias[n0 + wn * 128 + j * 16 + (lane & 15)] : 0.f;
        unsigned short* Cout = isQ ? (unsigned short*)Q : P;
        epilogue_bf16(acc, bvj, 0, smem, wave, lane, Cout, m0, n0, wm, wn, M, N);
    } else {
        // fp32 Q: scalar stores are 64 B per quarter-wave -> already coalesced
        const int col = lane & 15;
        const int rgrp = (lane >> 4) * 4;
        float* Qf = (float*)Q;
#pragma unroll
        for (int j = 0; j < 8; ++j) {
            int n = n0 + wn * 128 + j * 16 + col;
            float bv = bias[n];
#pragma unroll
            for (int i = 0; i < 4; ++i) {
                int mBase = m0 + wm * 64 + i * 16 + rgrp;
#pragma unroll
                for (int r = 0; r < 4; ++r) {
                    int m = mBase + r;
                    if (m >= M) continue;
                    Qf[(size_t)m * N + n] = acc[i][j][r] + bv;
                }
            }
        }
    }
}

// ---------------------------------------------------------------------------
extern "C" void kernel_launch(void* const* d_in, const int* in_sizes, int n_in,
                              void* d_out, int out_size, void* d_ws, size_t ws_size,
                              hipStream_t stream) {
    const float* x   = (const float*)d_in[0];
    const int*   e   = (const int*)d_in[1];
    const float* Wl0 = (const float*)d_in[2];
    const float* bl0 = (const float*)d_in[3];
    const float* Wr0 = (const float*)d_in[4];
    const float* Wl1 = (const float*)d_in[5];
    const float* bl1 = (const float*)d_in[6];
    const float* Wr1 = (const float*)d_in[7];
    const float* Wl2 = (const float*)d_in[8];
    const float* bl2 = (const float*)d_in[9];
    const float* Wr2 = (const float*)d_in[10];
    float* out = (float*)d_out;

    const int N = in_sizes[0] / 128;           // 50000 nodes
    const int E = in_sizes[1] / 2;             // 800000 edges
    const int Mpad = ((N + 127) / 128) * 128;  // 50048: GEMM staging never OOB

    char* ws = (char*)d_ws;
    size_t off = 0;
    auto alloc = [&](size_t bytes) { size_t o = off; off = align_up(off + bytes, 512); return o; };

    size_t o_nz     = alloc(4);
    size_t o_cnt    = alloc((size_t)N * 4);
    size_t o_cursor = alloc((size_t)N * 4);
    size_t zero_end = off;                       // [0, zero_end) zeroed each call
    size_t o_part   = alloc(1024 * 4);
    size_t o_offs   = alloc((size_t)(N + 1) * 4);
    size_t o_inv    = alloc((size_t)N * 4);
    size_t o_src    = alloc((size_t)E * 4);
    size_t o_dst    = alloc((size_t)E * 4);
    size_t o_sort   = alloc((size_t)E * 4);
    size_t o_xb     = alloc((size_t)Mpad * 128 * 2);   // bf16 x row-major
    size_t o_aggx   = alloc((size_t)Mpad * 128 * 2);   // bf16 agg(x)
    size_t o_h      = alloc((size_t)Mpad * 512 * 2);   // h0, then h1
    size_t o_P      = alloc((size_t)Mpad * 512 * 2);   // P1 (512), then P2 (256)
    size_t o_Q      = alloc((size_t)Mpad * 512 * 2);   // Q1 bf16 (512), then Q2 fp32 (256)
    size_t o_wl0    = alloc((size_t)512 * 128 * 2);
    size_t o_wr0    = alloc((size_t)512 * 128 * 2);
    size_t o_wl1    = alloc((size_t)512 * 512 * 2);
    size_t o_wr1    = alloc((size_t)512 * 512 * 2);
    size_t o_wl2    = alloc((size_t)256 * 512 * 2);
    size_t o_wr2    = alloc((size_t)256 * 512 * 2);
    (void)ws_size; (void)n_in; (void)out_size;

    int*            nz     = (int*)(ws + o_nz);
    int*            cnt    = (int*)(ws + o_cnt);
    int*            cursor = (int*)(ws + o_cursor);
    int*            part   = (int*)(ws + o_part);
    int*            offs   = (int*)(ws + o_offs);
    float*          inv    = (float*)(ws + o_inv);
    int*            src32  = (int*)(ws + o_src);
    int*            dst32  = (int*)(ws + o_dst);
    int*            sorted = (int*)(ws + o_sort);
    unsigned short* xb     = (unsigned short*)(ws + o_xb);
    unsigned short* aggx   = (unsigned short*)(ws + o_aggx);
    unsigned short* hbuf   = (unsigned short*)(ws + o_h);
    unsigned short* Pbuf   = (unsigned short*)(ws + o_P);
    unsigned short* Qbuf   = (unsigned short*)(ws + o_Q);   // bf16 view (layer 1)
    float*          Qf     = (float*)(ws + o_Q);            // fp32 view (layer 2)
    unsigned short* wl0b   = (unsigned short*)(ws + o_wl0);
    unsigned short* wr0b   = (unsigned short*)(ws + o_wr0);
    unsigned short* wl1b   = (unsigned short*)(ws + o_wl1);
    unsigned short* wr1b   = (unsigned short*)(ws + o_wr1);
    unsigned short* wl2b   = (unsigned short*)(ws + o_wl2);
    unsigned short* wr2b   = (unsigned short*)(ws + o_wr2);

    // zero nz/cnt/cursor (ws poisoned 0xAA before every call)
    int zn = (int)(zero_end / 4);
    zero_kernel<<<(zn + 255) / 256, 256, 0, stream>>>((int*)ws, zn);

    int eb = (E + 255) / 256;
    detect_kernel<<<1, 256, 0, stream>>>(e, nz, E);
    conv_count_kernel<<<eb, 256, 0, stream>>>(e, nz, src32, dst32, cnt, E);

    const int C = (N + 1023) / 1024;
    scan1_kernel<<<4, 256, 0, stream>>>(cnt, part, N, C);
    scan2_kernel<<<1, 1024, 0, stream>>>(part);
    scan3_kernel<<<4, 256, 0, stream>>>(cnt, part, offs, N, C, E);
    inv_kernel<<<(N + 255) / 256, 256, 0, stream>>>(cnt, inv, N);
    fill_kernel<<<eb, 256, 0, stream>>>(src32, dst32, offs, cursor, sorted, E);

    // conversions to bf16
    int n4 = N * 128 / 4;
    cvt_bf16_kernel<<<(n4 + 255) / 256, 256, 0, stream>>>(x, xb, n4);
    cvt_bf16_kernel<<<(512 * 128 / 4 + 255) / 256, 256, 0, stream>>>(Wl0, wl0b, 512 * 128 / 4);
    cvt_bf16_kernel<<<(512 * 128 / 4 + 255) / 256, 256, 0, stream>>>(Wr0, wr0b, 512 * 128 / 4);
    cvt_bf16_kernel<<<(512 * 512 / 4 + 255) / 256, 256, 0, stream>>>(Wl1, wl1b, 512 * 512 / 4);
    cvt_bf16_kernel<<<(512 * 512 / 4 + 255) / 256, 256, 0, stream>>>(Wr1, wr1b, 512 * 512 / 4);
    cvt_bf16_kernel<<<(256 * 512 / 4 + 255) / 256, 256, 0, stream>>>(Wl2, wl2b, 256 * 512 / 4);
    cvt_bf16_kernel<<<(256 * 512 / 4 + 255) / 256, 256, 0, stream>>>(Wr2, wr2b, 256 * 512 / 4);

    const int aggBlocks = (N + 3) / 4;
    const int mBlocks = Mpad / 128;

    // Layer 0: agg-then-GEMM (aggregating 128-dim x is the cheap side).
    agg128_kernel<<<aggBlocks, 256, 0, stream>>>(xb, sorted, offs, inv, aggx, N);
    sage_gemm_mfma<<<dim3(2, mBlocks), 256, 0, stream>>>(
        aggx, xb, wl0b, wr0b, bl0, hbuf, N, 512, 128);

    // Layer 1: GEMM-then-agg: P1=h0@Wl1^T, Q1=h0@Wr1^T+bl1;
    // h1 = relu(inv*sum P1[src] + Q1)
    dual_gemm_mfma<<<dim3(4, mBlocks), 256, 0, stream>>>(
        hbuf, wl1b, wr1b, bl1, Pbuf, Qbuf, N, 512, 512, 0);
    aggfuse512_kernel<<<aggBlocks, 256, 0, stream>>>(
        Pbuf, Qbuf, sorted, offs, inv, hbuf, N);

    // Layer 2: GEMM-then-agg at 256-dim (gather halved vs agg-first);
    // out = inv*sum P2[src] + Q2 (fp32, no relu)
    dual_gemm_mfma<<<dim3(2, mBlocks), 256, 0, stream>>>(
        hbuf, wl2b, wr2b, bl2, Pbuf, (void*)Qf, N, 256, 512, 1);
    aggfuse256_kernel<<<aggBlocks, 256, 0, stream>>>(
        Pbuf, Qf, sorted, offs, inv, out, N);
}